// Round 5
// baseline (416.982 us; speedup 1.0000x reference)
//
#include <hip/hip_runtime.h>
#include <hip/hip_bf16.h>

#define NNODES 8192
#define EMB    1024
#define HID    256

typedef float f32x4 __attribute__((ext_vector_type(4)));
typedef short bf16x8v __attribute__((ext_vector_type(8)));
typedef unsigned short u16x4 __attribute__((ext_vector_type(4)));
typedef unsigned short u16x8 __attribute__((ext_vector_type(8)));

static __device__ __forceinline__ unsigned short f2bf(float f) {
  union { float f; unsigned int u; } x; x.f = f;
  unsigned int r = (x.u + 0x7fffu + ((x.u >> 16) & 1u)) >> 16;
  return (unsigned short)r;
}

// ---------------------------------------------------------------------------
// Prep: Wt[n][k] = bf16(W[k][n]); init parent[] = -1; zero d_out.
// 64 blocks x 256 threads.
// ---------------------------------------------------------------------------
__global__ __launch_bounds__(256) void prep_wt(const float* __restrict__ W,
                                               unsigned short* __restrict__ Wt,
                                               int* __restrict__ parent,
                                               float* __restrict__ out) {
  int gid = blockIdx.x * 256 + threadIdx.x;          // 0..16383
  if (gid < NNODES) parent[gid] = -1;
  // zero out (8 MB): 524288 float4 / 16384 threads = 32 each, coalesced
  f32x4* o4 = (f32x4*)out;
  for (int i = gid; i < NNODES * HID / 4; i += 64 * 256) {
    f32x4 z = {0.f, 0.f, 0.f, 0.f};
    o4[i] = z;
  }

  __shared__ float lds[64 * 65];
  int k0 = (blockIdx.x >> 2) * 64;
  int n0 = (blockIdx.x & 3) * 64;
  int t = threadIdx.x;
#pragma unroll
  for (int p = 0; p < 4; p++) {
    int k = p * 16 + (t >> 4);
    int c4 = (t & 15) * 4;
    float4 v = *(const float4*)&W[(size_t)(k0 + k) * HID + n0 + c4];
    lds[k * 65 + c4 + 0] = v.x; lds[k * 65 + c4 + 1] = v.y;
    lds[k * 65 + c4 + 2] = v.z; lds[k * 65 + c4 + 3] = v.w;
  }
  __syncthreads();
  int n = t >> 2, kq = t & 3;
  u16x8 o0, o1;
#pragma unroll
  for (int i = 0; i < 8; i++) o0[i] = f2bf(lds[(kq * 16 + i) * 65 + n]);
#pragma unroll
  for (int i = 0; i < 8; i++) o1[i] = f2bf(lds[(kq * 16 + 8 + i) * 65 + n]);
  unsigned short* dst = &Wt[(size_t)(n0 + n) * EMB + k0 + kq * 16];
  *(u16x8*)(dst) = o0;
  *(u16x8*)(dst + 8) = o1;
}

// ---------------------------------------------------------------------------
// Fused: blocks [0,256) = bf16-MFMA GEMM h0 = relu(X@W+b) (f32 out);
// blocks [256, 256+8192) = adjacency extract: rowsum -> dinv, and for each
// nonzero (i,j): j==i -> sval[i]; j!=i -> parent[j]=i, pval[j]=val.
// (Tree: each j has exactly one parent -> no write races.)
// ---------------------------------------------------------------------------
#define GEMM_BLOCKS 256

__global__ __launch_bounds__(256) void fused_extract_gemm(
    const float* __restrict__ X, const unsigned short* __restrict__ Wt,
    const float* __restrict__ bias, const float* __restrict__ adj,
    float* __restrict__ h0, float* __restrict__ dinv,
    int* __restrict__ parent, float* __restrict__ pval,
    float* __restrict__ sval) {
  __shared__ char smem[24 * 1024 + 64];
  int t = threadIdx.x;

  if (blockIdx.x >= GEMM_BLOCKS) {
    // ---------------- extract path ----------------
    int row = blockIdx.x - GEMM_BLOCKS;
    float* s_part = (float*)smem;
    const float4* arow = (const float4*)(adj + (size_t)row * NNODES);
    float sum = 0.f;
    for (int c4 = t; c4 < NNODES / 4; c4 += 256) {
      float4 v = arow[c4];
      sum += v.x + v.y + v.z + v.w;
      int j0 = c4 * 4;
      if (v.x != 0.f) { if (j0 + 0 == row) sval[row] = v.x; else { parent[j0 + 0] = row; pval[j0 + 0] = v.x; } }
      if (v.y != 0.f) { if (j0 + 1 == row) sval[row] = v.y; else { parent[j0 + 1] = row; pval[j0 + 1] = v.y; } }
      if (v.z != 0.f) { if (j0 + 2 == row) sval[row] = v.z; else { parent[j0 + 2] = row; pval[j0 + 2] = v.z; } }
      if (v.w != 0.f) { if (j0 + 3 == row) sval[row] = v.w; else { parent[j0 + 3] = row; pval[j0 + 3] = v.w; } }
    }
    for (int off = 32; off > 0; off >>= 1) sum += __shfl_down(sum, off, 64);
    int wave = t >> 6;
    if ((t & 63) == 0) s_part[wave] = sum;
    __syncthreads();
    if (t == 0) {
      float tot = s_part[0] + s_part[1] + s_part[2] + s_part[3];
      dinv[row] = rsqrtf(tot);
    }
    return;
  }

  // ---------------- GEMM path: 128x64 tile, BK=64, bf16 MFMA ----------------
  unsigned short* As = (unsigned short*)smem;               // [128][64] bf16
  unsigned short* Bs = (unsigned short*)(smem + 16 * 1024); // [64][64] bf16 (B^T)
  int mb = blockIdx.x & 63, nb = blockIdx.x >> 6;
  int m0 = mb * 128, n0 = nb * 64;
  int w = t >> 6, l = t & 63;

  f32x4 acc[2][4] = {};

  for (int kt = 0; kt < EMB; kt += 64) {
    __syncthreads();
    {
      int c4 = t & 15;
#pragma unroll
      for (int rr = 0; rr < 8; rr++) {
        int row = rr * 16 + (t >> 4);
        float4 v = *(const float4*)&X[(size_t)(m0 + row) * EMB + kt + c4 * 4];
        u16x4 pk = {f2bf(v.x), f2bf(v.y), f2bf(v.z), f2bf(v.w)};
        int slot = ((c4 >> 1) + (row >> 1)) & 7;
        *(u16x4*)&As[row * 64 + slot * 8 + (c4 & 1) * 4] = pk;
      }
    }
    {
      int n = t >> 2, q = t & 3;
      const unsigned short* src = &Wt[(size_t)(n0 + n) * EMB + kt + q * 16];
#pragma unroll
      for (int e = 0; e < 2; e++) {
        u16x8 v = *(const u16x8*)(src + e * 8);
        int slot = ((q * 2 + e) + (n >> 1)) & 7;
        *(u16x8*)&Bs[n * 64 + slot * 8] = v;
      }
    }
    __syncthreads();
#pragma unroll
    for (int ks = 0; ks < 2; ks++) {
      bf16x8v a[2], b[4];
#pragma unroll
      for (int mf = 0; mf < 2; mf++) {
        int row = w * 32 + mf * 16 + (l & 15);
        int slot = ((ks * 4 + (l >> 4)) + (row >> 1)) & 7;
        a[mf] = *(bf16x8v*)&As[row * 64 + slot * 8];
      }
#pragma unroll
      for (int nf = 0; nf < 4; nf++) {
        int rowB = nf * 16 + (l & 15);
        int slot = ((ks * 4 + (l >> 4)) + (rowB >> 1)) & 7;
        b[nf] = *(bf16x8v*)&Bs[rowB * 64 + slot * 8];
      }
#pragma unroll
      for (int mf = 0; mf < 2; mf++)
#pragma unroll
        for (int nf = 0; nf < 4; nf++)
          acc[mf][nf] = __builtin_amdgcn_mfma_f32_16x16x32_bf16(a[mf], b[nf], acc[mf][nf], 0, 0, 0);
    }
  }
#pragma unroll
  for (int mf = 0; mf < 2; mf++)
#pragma unroll
    for (int nf = 0; nf < 4; nf++) {
      int r0 = m0 + w * 32 + mf * 16 + (l >> 4) * 4;
      int cc = n0 + nf * 16 + (l & 15);
      float bv = bias[cc];
#pragma unroll
      for (int r = 0; r < 4; r++)
        h0[(size_t)(r0 + r) * HID + cc] = fmaxf(acc[mf][nf][r] + bv, 0.f);
    }
}

// ---------------------------------------------------------------------------
// Closed-form 6-step APPNP scatter. M = 0.8^6 T^6 + 0.2 * sum_{k=0}^{5} 0.8^k T^k.
// For tree T = D^-1/2 (I-ish + C) D^-1/2, node j contributes only to its
// ancestors a_0=j..a_6:  coef_d = E_d * sum_{r=0}^{6-d} c_{d+r} * h_r(s_0..s_d)
// where s_m = dinv[a_m]^2*sval[a_m], E_d = prod of edge weights up the path,
// h_r = complete homogeneous symmetric polynomial (register DP).
// One wave per node; lane = 4 features; scatter via f32 atomicAdd.
// ---------------------------------------------------------------------------
__global__ __launch_bounds__(256) void scatter_prop(
    const float* __restrict__ h0, const float* __restrict__ dinv,
    const int* __restrict__ parent, const float* __restrict__ pval,
    const float* __restrict__ sval, float* __restrict__ out) {
  int w = threadIdx.x >> 6, l = threadIdx.x & 63;
  int j = blockIdx.x * 4 + w;

  // c_k: 0.2*0.8^k for k=0..5; 0.8^6 for k=6
  const float c0 = 0.2f, c1 = 0.16f, c2 = 0.128f, c3 = 0.1024f,
              c4 = 0.08192f, c5 = 0.065536f, c6 = 0.262144f;
  float cc[7] = {c0, c1, c2, c3, c4, c5, c6};

  float dj = dinv[j];
  float s0 = dj * dj * sval[j];
  float H[7];
  H[0] = 1.f;
#pragma unroll
  for (int r = 1; r <= 6; r++) H[r] = H[r - 1] * s0;
  float coef0 = 0.f;
#pragma unroll
  for (int r = 0; r <= 6; r++) coef0 += cc[r] * H[r];

  f32x4 hv = *(const f32x4*)&h0[(size_t)j * HID + l * 4];

  {
    float* orow = &out[(size_t)j * HID + l * 4];
    atomicAdd(&orow[0], coef0 * hv[0]);
    atomicAdd(&orow[1], coef0 * hv[1]);
    atomicAdd(&orow[2], coef0 * hv[2]);
    atomicAdd(&orow[3], coef0 * hv[3]);
  }

  int cur = j;
  float dprev = dj;
  float E = 1.f;
  for (int d = 1; d <= 6; d++) {
    int p = parent[cur];
    if (p < 0) break;
    float dp = dinv[p];
    E *= dp * dprev * pval[cur];     // T[a_d, a_{d-1}] edge weight
    float sd = dp * dp * sval[p];
    // H[r] <- h_r(s_0..s_d): in-place ascending r uses updated H[r-1]
#pragma unroll
    for (int r = 6; r >= 1; r--) {
      // note: must use ASCENDING update for the recurrence; do it explicitly:
    }
#pragma unroll
    for (int r = 1; r <= 6; r++) H[r] = H[r] + sd * H[r - 1];
    float cf = 0.f;
    for (int r = 0; r + d <= 6; r++) cf += cc[r + d] * H[r];
    cf *= E;
    float* prow = &out[(size_t)p * HID + l * 4];
    atomicAdd(&prow[0], cf * hv[0]);
    atomicAdd(&prow[1], cf * hv[1]);
    atomicAdd(&prow[2], cf * hv[2]);
    atomicAdd(&prow[3], cf * hv[3]);
    cur = p;
    dprev = dp;
  }
}

// ---------------------------------------------------------------------------
extern "C" void kernel_launch(void* const* d_in, const int* in_sizes, int n_in,
                              void* d_out, int out_size, void* d_ws, size_t ws_size,
                              hipStream_t stream) {
  const float* X    = (const float*)d_in[0];  // [8192,1024]
  const float* W    = (const float*)d_in[1];  // [1024,256]
  const float* bias = (const float*)d_in[2];  // [256]
  const float* adj  = (const float*)d_in[3];  // [8192,8192]
  float* out = (float*)d_out;                 // [8192,256]

  char* ws = (char*)d_ws;
  float*          h0     = (float*)(ws);                                  // 8 MB
  unsigned short* Wt     = (unsigned short*)(ws + (size_t)8 * 1024 * 1024);   // 512 KB
  float*          dinv   = (float*)(ws + (size_t)8704 * 1024);            // 32 KB
  int*            parent = (int*)  (ws + (size_t)8736 * 1024);            // 32 KB
  float*          pval   = (float*)(ws + (size_t)8768 * 1024);            // 32 KB
  float*          sval   = (float*)(ws + (size_t)8800 * 1024);            // 32 KB

  prep_wt<<<64, 256, 0, stream>>>(W, Wt, parent, out);
  fused_extract_gemm<<<GEMM_BLOCKS + NNODES, 256, 0, stream>>>(
      X, Wt, bias, adj, h0, dinv, parent, pval, sval);
  scatter_prop<<<NNODES / 4, 256, 0, stream>>>(h0, dinv, parent, pval, sval, out);
}